// Round 1
// baseline (1176.947 us; speedup 1.0000x reference)
//
#include <hip/hip_runtime.h>
#include <math.h>

// Problem constants: B=8, N=1024, C=768, H=8, hd=96
#define K_DIM 768
#define NQKV  2304
#define HD    96
#define NH    8
#define NSEQ  1024
#define NBATCH 8

// ---------------- 64x64x(K=768) fp32 tiled GEMM core ----------------
// 256 threads, 4x4 micro-tile per thread, K-step 16, float4 LDS reads.
template<int LDB>
__device__ __forceinline__ void gemm64x64(const float* __restrict__ A,
                                          const float* __restrict__ B,
                                          float acc[4][4], int m0, int n0)
{
    __shared__ float As[16][64];   // [k][m]
    __shared__ float Bs[16][64];   // [k][n]
    const int tid = threadIdx.x;
    const int tx = tid & 15, ty = tid >> 4;

#pragma unroll
    for (int i = 0; i < 4; ++i)
#pragma unroll
        for (int j = 0; j < 4; ++j) acc[i][j] = 0.f;

    for (int k0 = 0; k0 < K_DIM; k0 += 16) {
        __syncthreads();
        {
            // A tile: 64 rows x 16 k, store transposed As[k][m]
            const int r = tid >> 2, cg = tid & 3;
            const float4 a = *(const float4*)&A[(long)(m0 + r) * K_DIM + k0 + cg * 4];
            As[cg * 4 + 0][r] = a.x;
            As[cg * 4 + 1][r] = a.y;
            As[cg * 4 + 2][r] = a.z;
            As[cg * 4 + 3][r] = a.w;
            // B tile: 16 k-rows x 64 n, contiguous float4 store
            const int rb = tid >> 4, cb = tid & 15;
            *(float4*)&Bs[rb][cb * 4] = *(const float4*)&B[(long)(k0 + rb) * LDB + n0 + cb * 4];
        }
        __syncthreads();
#pragma unroll
        for (int kk = 0; kk < 16; ++kk) {
            const float4 a = *(const float4*)&As[kk][ty * 4];
            const float4 b = *(const float4*)&Bs[kk][tx * 4];
            const float av[4] = {a.x, a.y, a.z, a.w};
            const float bv[4] = {b.x, b.y, b.z, b.w};
#pragma unroll
            for (int i = 0; i < 4; ++i)
#pragma unroll
                for (int j = 0; j < 4; ++j)
                    acc[i][j] += av[i] * bv[j];
        }
    }
}

// ---------------- Kernel 1: qkv = x @ w_qkv, scatter to q/k/v [B,H,N,hd] ----
__global__ __launch_bounds__(256) void qkv_gemm_kernel(
    const float* __restrict__ x, const float* __restrict__ w,
    float* __restrict__ q, float* __restrict__ k, float* __restrict__ v)
{
    float acc[4][4];
    const int m0 = blockIdx.y * 64, n0 = blockIdx.x * 64;
    gemm64x64<NQKV>(x, w, acc, m0, n0);

    const int tx = threadIdx.x & 15, ty = threadIdx.x >> 4;
    const int col = n0 + tx * 4;                 // 0..2303, multiple of 4
    const int three = col / 768;
    const int rem = col - three * 768;
    const int h = rem / HD;
    const int d = rem - h * HD;                  // group of 4 never crosses head
    float* dst = (three == 0) ? q : ((three == 1) ? k : v);
#pragma unroll
    for (int i = 0; i < 4; ++i) {
        const int m = m0 + ty * 4 + i;           // 0..8191
        const int b = m >> 10, n = m & 1023;
        const float4 val = make_float4(acc[i][0], acc[i][1], acc[i][2], acc[i][3]);
        *(float4*)&dst[((long)(b * NH + h) * NSEQ + n) * HD + d] = val;
    }
}

// ---------------- Kernel 2: L2-normalize rows of q,k; fuse temperature into q
__global__ __launch_bounds__(256) void l2norm_kernel(
    float* __restrict__ q, float* __restrict__ k, const float* __restrict__ temp)
{
    const int wave = threadIdx.x >> 6;
    const int lane = threadIdx.x & 63;
    const long rowid = (long)blockIdx.x * 4 + wave;      // 0..131071
    const int which = (rowid >= 65536) ? 1 : 0;          // 0: q, 1: k
    const long r = which ? rowid - 65536 : rowid;        // 0..65535
    float* p = (which ? k : q) + r * HD;

    const float x0 = p[lane];
    const float x1 = (lane < 32) ? p[64 + lane] : 0.f;
    float s = x0 * x0 + x1 * x1;
#pragma unroll
    for (int off = 32; off > 0; off >>= 1) s += __shfl_xor(s, off);
    const float nrm = sqrtf(s);
    float scale = 1.f / fmaxf(nrm, 1e-12f);
    if (!which) {
        const int h = (int)((r >> 10) & 7);              // r = (b*8+h)*1024+n
        scale *= temp[h];
    }
    p[lane] = x0 * scale;
    if (lane < 32) p[64 + lane] = x1 * scale;
}

// ---------------- Kernel 3: fused attention (no-max online softmax) ---------
// One block = 256 query rows of one (b,h). q-row + O-accumulator in registers.
__global__ __launch_bounds__(256, 1) void attn_kernel(
    const float* __restrict__ q, const float* __restrict__ k,
    const float* __restrict__ v, float* __restrict__ ctx)
{
    __shared__ float kt[32][HD];
    __shared__ float vt[32][HD];
    const int bh  = blockIdx.x >> 2;                     // 0..63
    const int row = ((blockIdx.x & 3) << 8) + threadIdx.x;  // 0..1023
    const float* qp = q + ((long)bh * NSEQ + row) * HD;

    float qr[HD], acc[HD];
#pragma unroll
    for (int d = 0; d < HD; d += 4) {
        const float4 t = *(const float4*)&qp[d];
        qr[d] = t.x; qr[d + 1] = t.y; qr[d + 2] = t.z; qr[d + 3] = t.w;
        acc[d] = 0.f; acc[d + 1] = 0.f; acc[d + 2] = 0.f; acc[d + 3] = 0.f;
    }
    float denom = 0.f;

    for (int kt0 = 0; kt0 < NSEQ; kt0 += 32) {
        __syncthreads();
        {
            const float4* ksrc = (const float4*)(k + ((long)bh * NSEQ + kt0) * HD);
            const float4* vsrc = (const float4*)(v + ((long)bh * NSEQ + kt0) * HD);
            float4* kdst = (float4*)&kt[0][0];
            float4* vdst = (float4*)&vt[0][0];
            for (int t = threadIdx.x; t < 32 * HD / 4; t += 256) {
                kdst[t] = ksrc[t];
                vdst[t] = vsrc[t];
            }
        }
        __syncthreads();
#pragma unroll 2
        for (int j = 0; j < 32; ++j) {
            float s0 = 0.f, s1 = 0.f, s2 = 0.f, s3 = 0.f;
#pragma unroll
            for (int d = 0; d < HD; d += 4) {
                const float4 kv = *(const float4*)&kt[j][d];
                s0 += qr[d] * kv.x;
                s1 += qr[d + 1] * kv.y;
                s2 += qr[d + 2] * kv.z;
                s3 += qr[d + 3] * kv.w;
            }
            const float wgt = __expf(s0 + s1 + s2 + s3);  // |s|<=temp, no overflow
            denom += wgt;
#pragma unroll
            for (int d = 0; d < HD; d += 4) {
                const float4 vv = *(const float4*)&vt[j][d];
                acc[d]     += wgt * vv.x;
                acc[d + 1] += wgt * vv.y;
                acc[d + 2] += wgt * vv.z;
                acc[d + 3] += wgt * vv.w;
            }
        }
    }

    const float inv = 1.f / denom;
    const int b = bh >> 3, h = bh & 7;
    float* op = ctx + ((long)b * NSEQ + row) * K_DIM + h * HD;
#pragma unroll
    for (int d = 0; d < HD; d += 4) {
        const float4 val = make_float4(acc[d] * inv, acc[d + 1] * inv,
                                       acc[d + 2] * inv, acc[d + 3] * inv);
        *(float4*)&op[d] = val;
    }
}

// ---------------- Kernel 4: out = ctx @ w_proj + b_proj ---------------------
__global__ __launch_bounds__(256) void proj_gemm_kernel(
    const float* __restrict__ ctx, const float* __restrict__ w,
    const float* __restrict__ bias, float* __restrict__ out)
{
    float acc[4][4];
    const int m0 = blockIdx.y * 64, n0 = blockIdx.x * 64;
    gemm64x64<K_DIM>(ctx, w, acc, m0, n0);

    const int tx = threadIdx.x & 15, ty = threadIdx.x >> 4;
    const int col = n0 + tx * 4;
    const float4 bb = *(const float4*)&bias[col];
#pragma unroll
    for (int i = 0; i < 4; ++i) {
        const int m = m0 + ty * 4 + i;
        const float4 val = make_float4(acc[i][0] + bb.x, acc[i][1] + bb.y,
                                       acc[i][2] + bb.z, acc[i][3] + bb.w);
        *(float4*)&out[(long)m * K_DIM + col] = val;
    }
}

// ---------------- host launcher --------------------------------------------
extern "C" void kernel_launch(void* const* d_in, const int* in_sizes, int n_in,
                              void* d_out, int out_size, void* d_ws, size_t ws_size,
                              hipStream_t stream)
{
    const float* x      = (const float*)d_in[0];   // [8,1024,768]
    const float* w_qkv  = (const float*)d_in[1];   // [768,2304]
    const float* temp   = (const float*)d_in[2];   // [8,1,1]
    const float* w_proj = (const float*)d_in[3];   // [768,768]
    const float* b_proj = (const float*)d_in[4];   // [768]
    float* out = (float*)d_out;                    // [8,1024,768]

    const long PER = (long)NBATCH * NH * NSEQ * HD;  // 6291456 elements
    float* ws  = (float*)d_ws;
    float* q   = ws;
    float* k   = q + PER;
    float* v   = k + PER;
    float* ctx = v + PER;                          // [8,1024,768]

    // 1) qkv GEMM: [8192,768] @ [768,2304] -> q,k,v in [B,H,N,hd]
    qkv_gemm_kernel<<<dim3(NQKV / 64, 8192 / 64), dim3(256), 0, stream>>>(
        x, w_qkv, q, k, v);

    // 2) L2 normalize q (x temperature) and k: 131072 rows, 1 wave each
    l2norm_kernel<<<dim3(131072 / 4), dim3(256), 0, stream>>>(q, k, temp);

    // 3) fused attention -> ctx [B,N,C]
    attn_kernel<<<dim3(64 * 4), dim3(256), 0, stream>>>(q, k, v, ctx);

    // 4) projection GEMM + bias -> out
    proj_gemm_kernel<<<dim3(K_DIM / 64, 8192 / 64), dim3(256), 0, stream>>>(
        ctx, w_proj, b_proj, out);
}

// Round 2
// 290.570 us; speedup vs baseline: 4.0505x; 4.0505x over previous
//
#include <hip/hip_runtime.h>
#include <math.h>

typedef __attribute__((ext_vector_type(8))) short bf16x8;   // 8 bf16 = 4 VGPRs (MFMA A/B frag)
typedef __attribute__((ext_vector_type(4))) float f32x4;    // MFMA C/D frag
typedef unsigned short u16;
typedef unsigned int u32;

// Problem: B=8, N=1024, C=768, H=8, hd=96.  BH=64 combined batch-heads.

__device__ __forceinline__ u16 f2b(float f) {               // fp32 -> bf16 RNE
  u32 u = __float_as_uint(f);
  return (u16)((u + 0x7fffu + ((u >> 16) & 1u)) >> 16);
}
__device__ __forceinline__ float b2f(u16 h) {
  return __uint_as_float(((u32)h) << 16);
}

__device__ __forceinline__ void async16(const void* g, void* l) {
  // global -> LDS direct copy, 16B per lane; LDS dest = wave-uniform base + lane*16
  __builtin_amdgcn_global_load_lds((const __attribute__((address_space(1))) u32*)g,
                                   (__attribute__((address_space(3))) u32*)l, 16, 0, 0);
}

// ---------------- cast x fp32 -> bf16 (6291456 elements, 4/thread) ----------
__global__ __launch_bounds__(256) void cast_x_kernel(const float4* __restrict__ in,
                                                     uint2* __restrict__ out) {
  int idx = blockIdx.x * 256 + threadIdx.x;
  float4 v = in[idx];
  uint2 o;
  o.x = (u32)f2b(v.x) | ((u32)f2b(v.y) << 16);
  o.y = (u32)f2b(v.z) | ((u32)f2b(v.w) << 16);
  out[idx] = o;
}

// ---------------- transpose + cast: in[R][C] fp32 -> out[C][R] bf16 ---------
__global__ __launch_bounds__(256) void transpose_cast_kernel(const float* __restrict__ in,
                                                             u16* __restrict__ out,
                                                             int R, int C) {
  __shared__ float t[32][33];
  const int c0 = blockIdx.x * 32, r0 = blockIdx.y * 32;
  const int tc = threadIdx.x & 31, tr = threadIdx.x >> 5;
#pragma unroll
  for (int j = 0; j < 4; ++j)
    t[tr + j * 8][tc] = in[(size_t)(r0 + tr + j * 8) * C + c0 + tc];
  __syncthreads();
#pragma unroll
  for (int j = 0; j < 4; ++j)
    out[(size_t)(c0 + tr + j * 8) * R + r0 + tc] = f2b(t[tc][tr + j * 8]);
}

// ---------------- shared 128x128 bf16 MFMA GEMM core (K=768) ----------------
// A[m][768] bf16 row-major, Bt[n][768] bf16 row-major (pre-transposed B).
// 256 threads = 4 waves in 2x2; each wave 64x64 = 4x4 MFMA tiles of 16x16x32.
// LDS layout: XOR-swizzled 16B granules: slot(m,q) = 4m + (q ^ (m&3)) — keeps
// global_load_lds lane-contiguous AND makes ds_read_b128 frag reads uniform
// across bank windows (conflict-free).
__device__ __forceinline__ void gemm_core(const u16* __restrict__ A,
                                          const u16* __restrict__ Bt,
                                          int m0, int n0, f32x4 acc[4][4]) {
  __shared__ u16 As[128 * 32];
  __shared__ u16 Bs[128 * 32];
  const int tid = threadIdx.x;
  const int w = tid >> 6, lane = tid & 63;
  const int i15 = lane & 15, quad = lane >> 4;
  const int wm = (w >> 1) * 64, wn = (w & 1) * 64;
  const int sw = quad ^ (i15 & 3);      // fragment-read swizzle index

#pragma unroll
  for (int i = 0; i < 4; ++i)
#pragma unroll
    for (int j = 0; j < 4; ++j) acc[i][j] = (f32x4){0.f, 0.f, 0.f, 0.f};

  for (int k0 = 0; k0 < 768; k0 += 32) {
    __syncthreads();
#pragma unroll
    for (int rep = 0; rep < 2; ++rep) {
      const int j = rep * 256 + w * 64 + lane;   // linear granule slot
      const int m = j >> 2, e = j & 3;
      const int kg = e ^ (m & 3);                // which global granule lives here
      async16(A + ((size_t)(m0 + m) * 768 + k0 + kg * 8),
              (void*)(As + (size_t)(rep * 256 + w * 64) * 8));
      async16(Bt + ((size_t)(n0 + m) * 768 + k0 + kg * 8),
              (void*)(Bs + (size_t)(rep * 256 + w * 64) * 8));
    }
    __syncthreads();                              // drains vmcnt before reads
    bf16x8 af[4], bf[4];
#pragma unroll
    for (int i = 0; i < 4; ++i) {
      const int ml = wm + i * 16 + i15;
      af[i] = *(const bf16x8*)(As + (ml * 4 + sw) * 8);
      const int nl = wn + i * 16 + i15;
      bf[i] = *(const bf16x8*)(Bs + (nl * 4 + sw) * 8);
    }
#pragma unroll
    for (int i = 0; i < 4; ++i)
#pragma unroll
      for (int j = 0; j < 4; ++j)
        acc[i][j] = __builtin_amdgcn_mfma_f32_16x16x32_bf16(af[i], bf[j], acc[i][j], 0, 0, 0);
  }
}

// ---------------- qkv GEMM: xb[8192][768] @ wT -> q,k [bh][n][96], vT [bh][96][n]
__global__ __launch_bounds__(256, 3) void qkv_gemm_kernel(
    const u16* __restrict__ xb, const u16* __restrict__ wT,
    u16* __restrict__ q, u16* __restrict__ k, u16* __restrict__ vT) {
  f32x4 acc[4][4];
  const int m0 = blockIdx.y * 128, n0 = blockIdx.x * 128;
  gemm_core(xb, wT, m0, n0, acc);

  const int tid = threadIdx.x, w = tid >> 6, lane = tid & 63;
  const int i15 = lane & 15, quad = lane >> 4;
  const int wm = (w >> 1) * 64, wn = (w & 1) * 64;
#pragma unroll
  for (int jt = 0; jt < 4; ++jt) {
    const int cbase = n0 + wn + jt * 16;       // 16-col tile never crosses a head (96=6*16)
    const int three = cbase / 768;
    const int rem = cbase - three * 768;
    const int h = rem / 96;
    const int d = rem - h * 96 + i15;
#pragma unroll
    for (int it = 0; it < 4; ++it) {
#pragma unroll
      for (int r = 0; r < 4; ++r) {
        const int m = m0 + wm + it * 16 + quad * 4 + r;
        const int b = m >> 10, n = m & 1023;
        const int bh = b * 8 + h;
        const u16 val = f2b(acc[it][jt][r]);
        if (three == 0)      q[((size_t)bh * 1024 + n) * 96 + d] = val;
        else if (three == 1) k[((size_t)bh * 1024 + n) * 96 + d] = val;
        else                 vT[((size_t)bh * 96 + d) * 1024 + n] = val;  // transposed for PV
      }
    }
  }
}

// ---------------- L2 normalize q (x temperature) and k, bf16 in-place -------
__global__ __launch_bounds__(256) void l2norm_kernel(u32* __restrict__ q, u32* __restrict__ kk,
                                                     const float* __restrict__ temp) {
  const int wv = threadIdx.x >> 6, lane = threadIdx.x & 63;
  const long rowid = (long)blockIdx.x * 4 + wv;      // 0..131071
  const int isk = rowid >= 65536;
  const long r = isk ? rowid - 65536 : rowid;        // row = bh*1024 + n
  u32* p = (isk ? kk : q) + r * 48;                  // 96 bf16 = 48 dwords
  u32 d = 0; float f0 = 0.f, f1 = 0.f;
  if (lane < 48) {
    d = p[lane];
    f0 = b2f((u16)(d & 0xffffu));
    f1 = b2f((u16)(d >> 16));
  }
  float s = f0 * f0 + f1 * f1;
#pragma unroll
  for (int off = 32; off > 0; off >>= 1) s += __shfl_xor(s, off);
  float scale = 1.f / fmaxf(sqrtf(s), 1e-12f);
  if (!isk) scale *= temp[(int)((r >> 10) & 7)];     // fold temperature into q
  if (lane < 48)
    p[lane] = (u32)f2b(f0 * scale) | ((u32)f2b(f1 * scale) << 16);
}

// ---------------- fused attention, bf16 MFMA, no-max online softmax ---------
// Block: one (bh, 128 q-rows). 4 waves x 32 rows. K-tiles of 64 keys.
// S-phase computes S^T = K·Q^T (A=K LDS, B=Q regs) so C-layout regs are 4
// consecutive KEYS -> packed ds_write_b64 into Ps[qrow][key]; PV reads Ps as
// b128 A-frags and Vs (=V^T [d][key]) as B-frags. |logit|<=temp -> plain exp.
__global__ __launch_bounds__(256, 2) void attn_kernel(
    const u16* __restrict__ q, const u16* __restrict__ kk,
    const u16* __restrict__ vT, u16* __restrict__ ctx) {
  __shared__ u16 Ks[64 * 112];        // [key][d], stride 112 (16B-aligned, pad)
  __shared__ u16 Vs[96 * 72];         // [d][key], stride 72
  __shared__ u16 Ps[4][32 * 72];      // per-wave P [qrow][key], stride 72
  const int tid = threadIdx.x, w = tid >> 6, lane = tid & 63;
  const int i15 = lane & 15, quad = lane >> 4;
  const int bh = blockIdx.x >> 3, qbase = (blockIdx.x & 7) * 128;

  // Q fragments in registers: b_frag layout n=lane&15 -> qrow, k=quad*8+j -> d
  bf16x8 qf[2][3];
#pragma unroll
  for (int rt = 0; rt < 2; ++rt) {
    const int qrow = qbase + w * 32 + rt * 16 + i15;
    const u16* qp = q + ((size_t)bh * 1024 + qrow) * 96 + quad * 8;
#pragma unroll
    for (int c = 0; c < 3; ++c) qf[rt][c] = *(const bf16x8*)(qp + c * 32);
  }

  f32x4 o[2][6];
#pragma unroll
  for (int rt = 0; rt < 2; ++rt)
#pragma unroll
    for (int dt = 0; dt < 6; ++dt) o[rt][dt] = (f32x4){0.f, 0.f, 0.f, 0.f};
  float l[2] = {0.f, 0.f};

  // staging slot decomposition (768 16B-granules each for K and Vt)
  int kdiv[3], kmod[3], vdiv[3], vmod[3];
  uint4 kreg[3], vreg[3];
#pragma unroll
  for (int j = 0; j < 3; ++j) {
    const int s = tid + j * 256;
    kdiv[j] = s / 12; kmod[j] = s - kdiv[j] * 12;   // key row, 12x16B per row
    vdiv[j] = s >> 3; vmod[j] = s & 7;              // d row, 8x16B per row
  }

  // prefetch tile 0
  {
    const int kt0 = 0;
#pragma unroll
    for (int j = 0; j < 3; ++j) {
      kreg[j] = *(const uint4*)(kk + ((size_t)bh * 1024 + kt0 + kdiv[j]) * 96 + kmod[j] * 8);
      vreg[j] = *(const uint4*)(vT + ((size_t)bh * 96 + vdiv[j]) * 1024 + kt0 + vmod[j] * 8);
    }
  }

  for (int t = 0; t < 16; ++t) {
    __syncthreads();                    // all waves done reading prev K/Vs
#pragma unroll
    for (int j = 0; j < 3; ++j) {
      *(uint4*)(Ks + kdiv[j] * 112 + kmod[j] * 8) = kreg[j];
      *(uint4*)(Vs + vdiv[j] * 72 + vmod[j] * 8) = vreg[j];
    }
    __syncthreads();
    if (t < 15) {                       // prefetch next tile during compute
      const int kt0 = (t + 1) * 64;
#pragma unroll
      for (int j = 0; j < 3; ++j) {
        kreg[j] = *(const uint4*)(kk + ((size_t)bh * 1024 + kt0 + kdiv[j]) * 96 + kmod[j] * 8);
        vreg[j] = *(const uint4*)(vT + ((size_t)bh * 96 + vdiv[j]) * 1024 + kt0 + vmod[j] * 8);
      }
    }
    // ---- S^T phase: 4 key-tiles x 2 row-tiles x 3 d-chunks ----
#pragma unroll
    for (int kt = 0; kt < 4; ++kt) {
      bf16x8 af[3];                     // A=K: m=lane&15 -> key, k=quad*8+j -> d
#pragma unroll
      for (int c = 0; c < 3; ++c)
        af[c] = *(const bf16x8*)(Ks + (kt * 16 + i15) * 112 + c * 32 + quad * 8);
#pragma unroll
      for (int rt = 0; rt < 2; ++rt) {
        f32x4 s = (f32x4){0.f, 0.f, 0.f, 0.f};
#pragma unroll
        for (int c = 0; c < 3; ++c)
          s = __builtin_amdgcn_mfma_f32_16x16x32_bf16(af[c], qf[rt][c], s, 0, 0, 0);
        // C-layout: row=key=kt*16+quad*4+r, col=qrow=rt*16+i15
        const float e0 = __expf(s[0]), e1 = __expf(s[1]);
        const float e2 = __expf(s[2]), e3 = __expf(s[3]);
        l[rt] += (e0 + e1) + (e2 + e3);
        uint2 pk;
        pk.x = (u32)f2b(e0) | ((u32)f2b(e1) << 16);
        pk.y = (u32)f2b(e2) | ((u32)f2b(e3) << 16);
        *(uint2*)(Ps[w] + (rt * 16 + i15) * 72 + kt * 16 + quad * 4) = pk;
      }
    }
    // ---- PV phase: O[qrow][d] += P·V, 2 key-chunks x 6 d-tiles ----
#pragma unroll
    for (int c2 = 0; c2 < 2; ++c2) {
      bf16x8 pa[2];                     // A=P: m=lane&15 -> qrow, k -> key
#pragma unroll
      for (int rt = 0; rt < 2; ++rt)
        pa[rt] = *(const bf16x8*)(Ps[w] + (rt * 16 + i15) * 72 + c2 * 32 + quad * 8);
#pragma unroll
      for (int dt = 0; dt < 6; ++dt) {
        const bf16x8 vb = *(const bf16x8*)(Vs + (dt * 16 + i15) * 72 + c2 * 32 + quad * 8);
#pragma unroll
        for (int rt = 0; rt < 2; ++rt)
          o[rt][dt] = __builtin_amdgcn_mfma_f32_16x16x32_bf16(pa[rt], vb, o[rt][dt], 0, 0, 0);
      }
    }
  }

  // ---- epilogue: reduce l across the 16 key-lanes, divide, store bf16 ctx --
  l[0] += __shfl_xor(l[0], 16); l[0] += __shfl_xor(l[0], 32);
  l[1] += __shfl_xor(l[1], 16); l[1] += __shfl_xor(l[1], 32);
  const int b = bh >> 3, h = bh & 7;
#pragma unroll
  for (int rt = 0; rt < 2; ++rt) {
#pragma unroll
    for (int r = 0; r < 4; ++r) {
      const float linv = 1.f / __shfl(l[rt], quad * 4 + r);   // l lives at lane&15 == qrow%16
      const int row = b * 1024 + qbase + w * 32 + rt * 16 + quad * 4 + r;
#pragma unroll
      for (int dt = 0; dt < 6; ++dt)
        ctx[(size_t)row * 768 + h * 96 + dt * 16 + i15] = f2b(o[rt][dt][r] * linv);
    }
  }
}

// ---------------- proj GEMM: ctx[8192][768] @ wT + bias -> out fp32 ---------
__global__ __launch_bounds__(256, 3) void proj_gemm_kernel(
    const u16* __restrict__ ctx, const u16* __restrict__ wT,
    const float* __restrict__ bias, float* __restrict__ out) {
  f32x4 acc[4][4];
  const int m0 = blockIdx.y * 128, n0 = blockIdx.x * 128;
  gemm_core(ctx, wT, m0, n0, acc);

  const int tid = threadIdx.x, w = tid >> 6, lane = tid & 63;
  const int i15 = lane & 15, quad = lane >> 4;
  const int wm = (w >> 1) * 64, wn = (w & 1) * 64;
#pragma unroll
  for (int jt = 0; jt < 4; ++jt) {
    const int c = n0 + wn + jt * 16 + i15;
    const float bb = bias[c];
#pragma unroll
    for (int it = 0; it < 4; ++it) {
#pragma unroll
      for (int r = 0; r < 4; ++r) {
        const int m = m0 + wm + it * 16 + quad * 4 + r;
        out[(size_t)m * 768 + c] = acc[it][jt][r] + bb;
      }
    }
  }
}

// ---------------- host launcher --------------------------------------------
extern "C" void kernel_launch(void* const* d_in, const int* in_sizes, int n_in,
                              void* d_out, int out_size, void* d_ws, size_t ws_size,
                              hipStream_t stream) {
  const float* x      = (const float*)d_in[0];   // [8,1024,768]
  const float* w_qkv  = (const float*)d_in[1];   // [768,2304]
  const float* temp   = (const float*)d_in[2];   // [8]
  const float* w_proj = (const float*)d_in[3];   // [768,768]
  const float* b_proj = (const float*)d_in[4];   // [768]

  u16* ws      = (u16*)d_ws;
  u16* xb      = ws;                     // 8192*768
  u16* wqkvT   = xb + 6291456;           // 2304*768
  u16* qb      = wqkvT + 1769472;        // 64*1024*96
  u16* kb      = qb + 6291456;
  u16* vTb     = kb + 6291456;           // 64*96*1024 (transposed)
  u16* ctxb    = vTb + 6291456;          // 8192*768
  u16* wprojT  = ctxb + 6291456;         // 768*768

  cast_x_kernel<<<6144, 256, 0, stream>>>((const float4*)x, (uint2*)xb);
  transpose_cast_kernel<<<dim3(72, 24), 256, 0, stream>>>(w_qkv, wqkvT, 768, 2304);
  transpose_cast_kernel<<<dim3(24, 24), 256, 0, stream>>>(w_proj, wprojT, 768, 768);
  qkv_gemm_kernel<<<dim3(18, 64), 256, 0, stream>>>(xb, wqkvT, qb, kb, vTb);
  l2norm_kernel<<<32768, 256, 0, stream>>>((u32*)qb, (u32*)kb, temp);
  attn_kernel<<<512, 256, 0, stream>>>(qb, kb, vTb, ctxb);
  proj_gemm_kernel<<<dim3(6, 64), 256, 0, stream>>>(ctxb, wprojT, b_proj, (float*)d_out);
}

// Round 3
// 259.234 us; speedup vs baseline: 4.5401x; 1.1209x over previous
//
#include <hip/hip_runtime.h>
#include <math.h>

typedef __attribute__((ext_vector_type(8))) short bf16x8;   // 8 bf16 = 4 VGPRs (MFMA A/B frag)
typedef __attribute__((ext_vector_type(4))) float f32x4;    // MFMA C/D frag
typedef unsigned short u16;
typedef unsigned int u32;

// Problem: B=8, N=1024, C=768, H=8, hd=96.  BH=64 combined batch-heads.

__device__ __forceinline__ u16 f2b(float f) {               // fp32 -> bf16 RNE
  u32 u = __float_as_uint(f);
  return (u16)((u + 0x7fffu + ((u >> 16) & 1u)) >> 16);
}
__device__ __forceinline__ float b2f(u16 h) {
  return __uint_as_float(((u32)h) << 16);
}
__device__ __forceinline__ int swz(int m) { return (m ^ (m >> 2)) & 3; }

__device__ __forceinline__ void async16(const void* g, void* l) {
  __builtin_amdgcn_global_load_lds((const __attribute__((address_space(1))) u32*)g,
                                   (__attribute__((address_space(3))) u32*)l, 16, 0, 0);
}

// ---------------- prep: cast x, transpose+cast w_qkv and w_proj -------------
__global__ __launch_bounds__(256) void prep_kernel(const float* __restrict__ x,
                                                   const float* __restrict__ w_qkv,
                                                   const float* __restrict__ w_proj,
                                                   u16* __restrict__ xb,
                                                   u16* __restrict__ wqkvT,
                                                   u16* __restrict__ wprojT) {
  __shared__ float t[32][33];
  const int blk = blockIdx.x;
  if (blk < 6144) {                       // cast x -> bf16
    const int idx = blk * 256 + threadIdx.x;
    const float4 v = ((const float4*)x)[idx];
    uint2 o;
    o.x = (u32)f2b(v.x) | ((u32)f2b(v.y) << 16);
    o.y = (u32)f2b(v.z) | ((u32)f2b(v.w) << 16);
    ((uint2*)xb)[idx] = o;
    return;
  }
  const float* in; u16* out; int R, C, bx, by;
  if (blk < 6144 + 1728) {                // w_qkv [768,2304] -> [2304,768]
    const int rem = blk - 6144;
    in = w_qkv; out = wqkvT; R = 768; C = 2304; bx = rem % 72; by = rem / 72;
  } else {                                // w_proj [768,768] -> [768,768]
    const int rem = blk - 6144 - 1728;
    in = w_proj; out = wprojT; R = 768; C = 768; bx = rem % 24; by = rem / 24;
  }
  const int c0 = bx * 32, r0 = by * 32;
  const int tc = threadIdx.x & 31, tr = threadIdx.x >> 5;
#pragma unroll
  for (int j = 0; j < 4; ++j)
    t[tr + j * 8][tc] = in[(size_t)(r0 + tr + j * 8) * C + c0 + tc];
  __syncthreads();
#pragma unroll
  for (int j = 0; j < 4; ++j)
    out[(size_t)(c0 + tr + j * 8) * R + r0 + tc] = f2b(t[tc][tr + j * 8]);
}

// ---------------- shared 128x128 bf16 MFMA GEMM core (K=768) ----------------
// Granule XOR swizzle x(m)=(m^(m>>2))&3: b128 frag reads hit 8 bank windows
// x 2 lanes (2-way = free), staging stays lane-contiguous for global_load_lds.
__device__ __forceinline__ void gemm_core(const u16* __restrict__ A,
                                          const u16* __restrict__ Bt,
                                          int m0, int n0, f32x4 acc[4][4]) {
  __shared__ u16 As[128 * 32];
  __shared__ u16 Bs[128 * 32];
  const int tid = threadIdx.x;
  const int w = tid >> 6, lane = tid & 63;
  const int i15 = lane & 15, quad = lane >> 4;
  const int wm = (w >> 1) * 64, wn = (w & 1) * 64;
  const int sw = quad ^ ((i15 ^ (i15 >> 2)) & 3);

#pragma unroll
  for (int i = 0; i < 4; ++i)
#pragma unroll
    for (int j = 0; j < 4; ++j) acc[i][j] = (f32x4){0.f, 0.f, 0.f, 0.f};

  for (int k0 = 0; k0 < 768; k0 += 32) {
    __syncthreads();
#pragma unroll
    for (int rep = 0; rep < 2; ++rep) {
      const int j = rep * 256 + w * 64 + lane;   // linear granule slot
      const int m = j >> 2, e = j & 3;
      const int kg = e ^ swz(m);                 // which global granule lives here
      async16(A + ((size_t)(m0 + m) * 768 + k0 + kg * 8),
              (void*)(As + (size_t)(rep * 256 + w * 64) * 8));
      async16(Bt + ((size_t)(n0 + m) * 768 + k0 + kg * 8),
              (void*)(Bs + (size_t)(rep * 256 + w * 64) * 8));
    }
    __syncthreads();                              // drains vmcnt before reads
    bf16x8 af[4], bf[4];
#pragma unroll
    for (int i = 0; i < 4; ++i) {
      const int ml = wm + i * 16 + i15;
      af[i] = *(const bf16x8*)(As + ((size_t)ml * 4 + sw) * 8);
      const int nl = wn + i * 16 + i15;
      bf[i] = *(const bf16x8*)(Bs + ((size_t)nl * 4 + sw) * 8);
    }
#pragma unroll
    for (int i = 0; i < 4; ++i)
#pragma unroll
      for (int j = 0; j < 4; ++j)
        acc[i][j] = __builtin_amdgcn_mfma_f32_16x16x32_bf16(af[i], bf[j], acc[i][j], 0, 0, 0);
  }
}

// ---------------- qkv GEMM: xb[8192][768] @ wT -> q,k [bh][n][96], vT [bh][96][n]
__global__ __launch_bounds__(256, 3) void qkv_gemm_kernel(
    const u16* __restrict__ xb, const u16* __restrict__ wT,
    u16* __restrict__ q, u16* __restrict__ k, u16* __restrict__ vT) {
  f32x4 acc[4][4];
  const int m0 = blockIdx.y * 128, n0 = blockIdx.x * 128;
  gemm_core(xb, wT, m0, n0, acc);

  const int tid = threadIdx.x, w = tid >> 6, lane = tid & 63;
  const int i15 = lane & 15, quad = lane >> 4;
  const int wm = (w >> 1) * 64, wn = (w & 1) * 64;
#pragma unroll
  for (int jt = 0; jt < 4; ++jt) {
    const int cbase = n0 + wn + jt * 16;       // 16-col tile never crosses a head (96=6*16)
    const int three = cbase / 768;
    const int rem = cbase - three * 768;
    const int h = rem / 96;
    const int d = rem - h * 96 + i15;
#pragma unroll
    for (int it = 0; it < 4; ++it) {
#pragma unroll
      for (int r = 0; r < 4; ++r) {
        const int m = m0 + wm + it * 16 + quad * 4 + r;
        const int b = m >> 10, n = m & 1023;
        const int bh = b * 8 + h;
        const u16 val = f2b(acc[it][jt][r]);
        if (three == 0)      q[((size_t)bh * 1024 + n) * 96 + d] = val;
        else if (three == 1) k[((size_t)bh * 1024 + n) * 96 + d] = val;
        else                 vT[((size_t)bh * 96 + d) * 1024 + n] = val;  // transposed for PV
      }
    }
  }
}

// ---------------- L2 normalize q (x temperature) and k, bf16 in-place -------
__global__ __launch_bounds__(256) void l2norm_kernel(u32* __restrict__ q, u32* __restrict__ kk,
                                                     const float* __restrict__ temp) {
  const int wv = threadIdx.x >> 6, lane = threadIdx.x & 63;
  const long rowid = (long)blockIdx.x * 4 + wv;      // 0..131071
  const int isk = rowid >= 65536;
  const long r = isk ? rowid - 65536 : rowid;        // row = bh*1024 + n
  u32* p = (isk ? kk : q) + r * 48;                  // 96 bf16 = 48 dwords
  u32 d = 0; float f0 = 0.f, f1 = 0.f;
  if (lane < 48) {
    d = p[lane];
    f0 = b2f((u16)(d & 0xffffu));
    f1 = b2f((u16)(d >> 16));
  }
  float s = f0 * f0 + f1 * f1;
#pragma unroll
  for (int off = 32; off > 0; off >>= 1) s += __shfl_xor(s, off);
  float scale = 1.f / fmaxf(sqrtf(s), 1e-12f);
  if (!isk) scale *= temp[(int)((r >> 10) & 7)];     // fold temperature into q
  if (lane < 48)
    p[lane] = (u32)f2b(f0 * scale) | ((u32)f2b(f1 * scale) << 16);
}

// ---------------- fused attention, bf16 MFMA, no-max online softmax ---------
// Block = (bh, 128 q-rows); bh = blockIdx&63 so the 8 q-blocks of one bh share
// an XCD (L2-resident K/V). S^T = K*Q^T (C-regs = 4 consecutive keys) -> exp ->
// packed b64 into per-wave Ps -> PV with A=P, B=V^T. All LDS layouts use the
// swz() granule XOR (2-way max). Epilogue goes through LDS for coalesced
// uint4 ctx stores.
__global__ __launch_bounds__(256, 2) void attn_kernel(
    const u16* __restrict__ q, const u16* __restrict__ kk,
    const u16* __restrict__ vT, u16* __restrict__ ctx) {
  __shared__ u16 smem[20480];         // [0,12288): K(768 gr)+V(768 gr); [12288,20480): Ps 4x256 gr
  u16* KVs = smem;
  const int tid = threadIdx.x, w = tid >> 6, lane = tid & 63;
  const int i15 = lane & 15, quad = lane >> 4;
  const int xs = (i15 ^ (i15 >> 2)) & 3;
  const int bh = blockIdx.x & 63, qbase = (blockIdx.x >> 6) * 128;
  const int b = bh >> 3, h = bh & 7;
  u16* Pw = smem + 12288 + w * 2048;  // per-wave P: 256 granules

  // Q fragments in registers: B-frag n=i15 -> qrow, k=quad*8+j -> d
  bf16x8 qf[2][3];
#pragma unroll
  for (int rt = 0; rt < 2; ++rt) {
    const int qrow = qbase + w * 32 + rt * 16 + i15;
    const u16* qp = q + ((size_t)bh * 1024 + qrow) * 96 + quad * 8;
#pragma unroll
    for (int c = 0; c < 3; ++c) qf[rt][c] = *(const bf16x8*)(qp + c * 32);
  }

  f32x4 o[2][6];
#pragma unroll
  for (int rt = 0; rt < 2; ++rt)
#pragma unroll
    for (int dt = 0; dt < 6; ++dt) o[rt][dt] = (f32x4){0.f, 0.f, 0.f, 0.f};
  float l[2] = {0.f, 0.f};

  // staging decomposition: K granule slot = c*256+tid, c=j; V slot = 768+j*256+tid
  const int key_s = tid >> 2, qs = tid & 3;
  const int kgq = qs ^ swz(key_s);
  int vd[3], vc2[3], vgq[3];
  vd[0] = tid >> 2;                      vc2[0] = 0;
  vd[1] = (tid < 128) ? (tid >> 2) + 64 : (tid >> 2) - 32;  vc2[1] = (tid >= 128);
  vd[2] = (tid >> 2) + 32;               vc2[2] = 1;
#pragma unroll
  for (int j = 0; j < 3; ++j) vgq[j] = qs ^ swz(vd[j]);

  uint4 kreg[3], vreg[3];
#pragma unroll
  for (int j = 0; j < 3; ++j) {          // prefetch tile 0
    kreg[j] = *(const uint4*)(kk + ((size_t)bh * 1024 + key_s) * 96 + (j * 4 + kgq) * 8);
    vreg[j] = *(const uint4*)(vT + ((size_t)bh * 96 + vd[j]) * 1024 + vc2[j] * 32 + vgq[j] * 8);
  }

  for (int t = 0; t < 16; ++t) {
    __syncthreads();                     // all waves done reading prev tile
#pragma unroll
    for (int j = 0; j < 3; ++j) {
      *(uint4*)(KVs + (size_t)(j * 256 + tid) * 8) = kreg[j];
      *(uint4*)(KVs + (size_t)(768 + j * 256 + tid) * 8) = vreg[j];
    }
    __syncthreads();
    if (t < 15) {                        // prefetch next tile during compute
      const int kt0 = (t + 1) * 64;
#pragma unroll
      for (int j = 0; j < 3; ++j) {
        kreg[j] = *(const uint4*)(kk + ((size_t)bh * 1024 + kt0 + key_s) * 96 + (j * 4 + kgq) * 8);
        vreg[j] = *(const uint4*)(vT + ((size_t)bh * 96 + vd[j]) * 1024 + kt0 + vc2[j] * 32 + vgq[j] * 8);
      }
    }
    // ---- S^T phase ----
#pragma unroll
    for (int kt = 0; kt < 4; ++kt) {
      bf16x8 af[3];                      // A=K: m=i15 -> key, k=quad*8+j -> d
#pragma unroll
      for (int c = 0; c < 3; ++c)
        af[c] = *(const bf16x8*)(KVs + ((size_t)((c * 64 + kt * 16 + i15) * 4) + (quad ^ xs)) * 8);
#pragma unroll
      for (int rt = 0; rt < 2; ++rt) {
        f32x4 s = (f32x4){0.f, 0.f, 0.f, 0.f};
#pragma unroll
        for (int c = 0; c < 3; ++c)
          s = __builtin_amdgcn_mfma_f32_16x16x32_bf16(af[c], qf[rt][c], s, 0, 0, 0);
        // C-layout: row=key=kt*16+quad*4+r, col=qrow=rt*16+i15
        const float e0 = __expf(s[0]), e1 = __expf(s[1]);
        const float e2 = __expf(s[2]), e3 = __expf(s[3]);
        l[rt] += (e0 + e1) + (e2 + e3);
        uint2 pk;
        pk.x = (u32)f2b(e0) | ((u32)f2b(e1) << 16);
        pk.y = (u32)f2b(e2) | ((u32)f2b(e3) << 16);
        const int pg = (kt & 1) * 2 + (quad >> 1);           // granule within key-chunk
        *(uint2*)(Pw + (size_t)(((kt >> 1) * 32 + rt * 16 + i15) * 4 + (pg ^ xs)) * 8
                      + (quad & 1) * 4) = pk;
      }
    }
    // ---- PV phase ----
#pragma unroll
    for (int c2 = 0; c2 < 2; ++c2) {
      bf16x8 pa[2];                      // A=P: m=i15 -> qrow, k -> key
#pragma unroll
      for (int rt = 0; rt < 2; ++rt)
        pa[rt] = *(const bf16x8*)(Pw + (size_t)((c2 * 32 + rt * 16 + i15) * 4 + (quad ^ xs)) * 8);
#pragma unroll
      for (int dt = 0; dt < 6; ++dt) {
        const bf16x8 vb = *(const bf16x8*)(KVs +
            ((size_t)(768 + (c2 * 96 + dt * 16 + i15) * 4) + (quad ^ xs)) * 8);
#pragma unroll
        for (int rt = 0; rt < 2; ++rt)
          o[rt][dt] = __builtin_amdgcn_mfma_f32_16x16x32_bf16(pa[rt], vb, o[rt][dt], 0, 0, 0);
      }
    }
  }

  // ---- epilogue: reduce l, scale, LDS round-trip, coalesced uint4 stores ---
  l[0] += __shfl_xor(l[0], 16); l[0] += __shfl_xor(l[0], 32);
  l[1] += __shfl_xor(l[1], 16); l[1] += __shfl_xor(l[1], 32);
  __syncthreads();                       // everyone past last PV; smem reusable
  u16* scr = smem + w * 5120;            // 32 rows x stride 104 (16B-aligned)
#pragma unroll
  for (int rt = 0; rt < 2; ++rt) {
#pragma unroll
    for (int r = 0; r < 4; ++r) {
      const float linv = 1.f / __shfl(l[rt], quad * 4 + r);
      const int row32 = rt * 16 + quad * 4 + r;
#pragma unroll
      for (int dt = 0; dt < 6; ++dt)
        scr[row32 * 104 + dt * 16 + i15] = f2b(o[rt][dt][r] * linv);
    }
  }
#pragma unroll
  for (int jj = 0; jj < 6; ++jj) {       // 384 uint4 per wave, 192B/row coalesced
    const int id = jj * 64 + lane;
    const int row32 = id / 12, g = id - row32 * 12;
    const int grow = b * 1024 + qbase + w * 32 + row32;
    *(uint4*)(ctx + (size_t)grow * 768 + h * 96 + g * 8) =
        *(const uint4*)(scr + row32 * 104 + g * 8);
  }
}

// ---------------- proj GEMM: ctx[8192][768] @ wT + bias -> out fp32 ---------
__global__ __launch_bounds__(256, 3) void proj_gemm_kernel(
    const u16* __restrict__ ctx, const u16* __restrict__ wT,
    const float* __restrict__ bias, float* __restrict__ out) {
  f32x4 acc[4][4];
  const int m0 = blockIdx.y * 128, n0 = blockIdx.x * 128;
  gemm_core(ctx, wT, m0, n0, acc);

  const int tid = threadIdx.x, w = tid >> 6, lane = tid & 63;
  const int i15 = lane & 15, quad = lane >> 4;
  const int wm = (w >> 1) * 64, wn = (w & 1) * 64;
#pragma unroll
  for (int jt = 0; jt < 4; ++jt) {
    const int c = n0 + wn + jt * 16 + i15;
    const float bb = bias[c];
#pragma unroll
    for (int it = 0; it < 4; ++it) {
#pragma unroll
      for (int r = 0; r < 4; ++r) {
        const int m = m0 + wm + it * 16 + quad * 4 + r;
        out[(size_t)m * 768 + c] = acc[it][jt][r] + bb;
      }
    }
  }
}

// ---------------- host launcher --------------------------------------------
extern "C" void kernel_launch(void* const* d_in, const int* in_sizes, int n_in,
                              void* d_out, int out_size, void* d_ws, size_t ws_size,
                              hipStream_t stream) {
  const float* x      = (const float*)d_in[0];   // [8,1024,768]
  const float* w_qkv  = (const float*)d_in[1];   // [768,2304]
  const float* temp   = (const float*)d_in[2];   // [8]
  const float* w_proj = (const float*)d_in[3];   // [768,768]
  const float* b_proj = (const float*)d_in[4];   // [768]

  u16* ws      = (u16*)d_ws;
  u16* xb      = ws;                     // 8192*768
  u16* wqkvT   = xb + 6291456;           // 2304*768
  u16* qb      = wqkvT + 1769472;        // 64*1024*96
  u16* kb      = qb + 6291456;
  u16* vTb     = kb + 6291456;           // 64*96*1024 (transposed)
  u16* ctxb    = vTb + 6291456;          // 8192*768
  u16* wprojT  = ctxb + 6291456;         // 768*768

  prep_kernel<<<8448, 256, 0, stream>>>(x, w_qkv, w_proj, xb, wqkvT, wprojT);
  qkv_gemm_kernel<<<dim3(18, 64), 256, 0, stream>>>(xb, wqkvT, qb, kb, vTb);
  l2norm_kernel<<<32768, 256, 0, stream>>>((u32*)qb, (u32*)kb, temp);
  attn_kernel<<<512, 256, 0, stream>>>(qb, kb, vTb, ctxb);
  proj_gemm_kernel<<<dim3(6, 64), 256, 0, stream>>>(ctxb, wprojT, b_proj, (float*)d_out);
}

// Round 4
// 206.802 us; speedup vs baseline: 5.6912x; 1.2535x over previous
//
#include <hip/hip_runtime.h>
#include <math.h>

typedef __attribute__((ext_vector_type(8))) short bf16x8;   // 8 bf16 = 4 VGPRs (MFMA A/B frag)
typedef __attribute__((ext_vector_type(4))) float f32x4;    // MFMA C/D frag
typedef unsigned short u16;
typedef unsigned int u32;

// Problem: B=8, N=1024, C=768, H=8, hd=96.  BH=64 combined batch-heads.

__device__ __forceinline__ u16 f2b(float f) {               // fp32 -> bf16 RNE
  u32 u = __float_as_uint(f);
  return (u16)((u + 0x7fffu + ((u >> 16) & 1u)) >> 16);
}
__device__ __forceinline__ float b2f(u16 h) {
  return __uint_as_float(((u32)h) << 16);
}
__device__ __forceinline__ int swz(int m) { return (m ^ (m >> 2)) & 3; }

__device__ __forceinline__ void async16(const void* g, void* l) {
  __builtin_amdgcn_global_load_lds((const __attribute__((address_space(1))) u32*)g,
                                   (__attribute__((address_space(3))) u32*)l, 16, 0, 0);
}

// ---------------- prep: cast x, transpose+cast w_qkv and w_proj -------------
__global__ __launch_bounds__(256) void prep_kernel(const float* __restrict__ x,
                                                   const float* __restrict__ w_qkv,
                                                   const float* __restrict__ w_proj,
                                                   u16* __restrict__ xb,
                                                   u16* __restrict__ wqkvT,
                                                   u16* __restrict__ wprojT) {
  __shared__ float t[32][33];
  const int blk = blockIdx.x;
  if (blk < 6144) {                       // cast x -> bf16
    const int idx = blk * 256 + threadIdx.x;
    const float4 v = ((const float4*)x)[idx];
    uint2 o;
    o.x = (u32)f2b(v.x) | ((u32)f2b(v.y) << 16);
    o.y = (u32)f2b(v.z) | ((u32)f2b(v.w) << 16);
    ((uint2*)xb)[idx] = o;
    return;
  }
  const float* in; u16* out; int R, C, bx, by;
  if (blk < 6144 + 1728) {                // w_qkv [768,2304] -> [2304,768]
    const int rem = blk - 6144;
    in = w_qkv; out = wqkvT; R = 768; C = 2304; bx = rem % 72; by = rem / 72;
  } else {                                // w_proj [768,768] -> [768,768]
    const int rem = blk - 6144 - 1728;
    in = w_proj; out = wprojT; R = 768; C = 768; bx = rem % 24; by = rem / 24;
  }
  const int c0 = bx * 32, r0 = by * 32;
  const int tc = threadIdx.x & 31, tr = threadIdx.x >> 5;
#pragma unroll
  for (int j = 0; j < 4; ++j)
    t[tr + j * 8][tc] = in[(size_t)(r0 + tr + j * 8) * C + c0 + tc];
  __syncthreads();
#pragma unroll
  for (int j = 0; j < 4; ++j)
    out[(size_t)(c0 + tr + j * 8) * R + r0 + tc] = f2b(t[tc][tr + j * 8]);
}

// ---------------- 128xNT bf16 MFMA GEMM core (K=768), NT in {64,192} --------
// Unified LDS granule array: A slots [0,512), B slots [512,512+NT*4).
// Granule XOR swizzle x(m)=(m^(m>>2))&3 keeps frag ds_read_b128 clean while
// staging stays lane-contiguous for global_load_lds (wave-uniform base).
template<int NT>
__device__ __forceinline__ void gemm_core(const u16* __restrict__ A,
                                          const u16* __restrict__ Bt,
                                          int m0, int n0, f32x4 acc[4][NT / 32]) {
  constexpr int JT = NT / 32;
  constexpr int NINST = (512 + NT * 4) / 256;
  __shared__ u16 Sm[(512 + NT * 4) * 8];
  const int tid = threadIdx.x;
  const int w = tid >> 6, lane = tid & 63;
  const int i15 = lane & 15, quad = lane >> 4;
  const int wm = (w >> 1) * 64, wn = (w & 1) * (NT / 2);
  const int sw = quad ^ swz(i15);

#pragma unroll
  for (int i = 0; i < 4; ++i)
#pragma unroll
    for (int j = 0; j < JT; ++j) acc[i][j] = (f32x4){0.f, 0.f, 0.f, 0.f};

  for (int k0 = 0; k0 < 768; k0 += 32) {
    __syncthreads();
#pragma unroll
    for (int inst = 0; inst < NINST; ++inst) {
      const int s = inst * 256 + tid;          // granule slot (per lane)
      const u16* src;
      if (inst < 2) {                          // A region (slots < 512)
        const int m = s >> 2, e = s & 3;
        src = A + ((size_t)(m0 + m) * 768 + k0 + (e ^ swz(m)) * 8);
      } else {                                 // B region
        const int s2 = s - 512;
        const int n = s2 >> 2, e = s2 & 3;
        src = Bt + ((size_t)(n0 + n) * 768 + k0 + (e ^ swz(n)) * 8);
      }
      async16(src, (void*)(Sm + (size_t)(inst * 256 + w * 64) * 8));
    }
    __syncthreads();                           // drains vmcnt before reads
    bf16x8 af[4], bf[JT];
#pragma unroll
    for (int i = 0; i < 4; ++i)
      af[i] = *(const bf16x8*)(Sm + ((size_t)(wm + i * 16 + i15) * 4 + sw) * 8);
#pragma unroll
    for (int j = 0; j < JT; ++j)
      bf[j] = *(const bf16x8*)(Sm + ((size_t)512 + (wn + j * 16 + i15) * 4 + sw) * 8);
#pragma unroll
    for (int i = 0; i < 4; ++i)
#pragma unroll
      for (int j = 0; j < JT; ++j)
        acc[i][j] = __builtin_amdgcn_mfma_f32_16x16x32_bf16(af[i], bf[j], acc[i][j], 0, 0, 0);
  }
}

// ---------------- qkv GEMM + fused L2norm/temp epilogue ---------------------
// Tile 128x192: N-tile = exactly 2 heads -> each wave owns one head's full
// 96-d rows. Rows live in 16 lanes sharing quad -> sumsq = in-thread over jt
// + shfl_xor(1,2,4,8). q gets temp[h] folded; v written transposed (packed).
__global__ __launch_bounds__(256, 3) void qkv_gemm_kernel(
    const u16* __restrict__ xb, const u16* __restrict__ wT,
    const float* __restrict__ temp,
    u16* __restrict__ q, u16* __restrict__ k, u16* __restrict__ vT) {
  f32x4 acc[4][6];
  const int bid = blockIdx.x;                 // 768 blocks = 3/CU exact
  const int xcd = bid & 7, slot = bid >> 3;   // 96 slots per XCD
  const int mb = xcd * 8 + slot / 12, nb = slot % 12;
  const int m0 = mb * 128, n0 = nb * 192;
  gemm_core<192>(xb, wT, m0, n0, acc);

  const int tid = threadIdx.x, w = tid >> 6, lane = tid & 63;
  const int i15 = lane & 15, quad = lane >> 4;
  const int wm = (w >> 1) * 64;
  const int three = nb >> 2;                  // 0=q, 1=k, 2=v
  const int h = ((nb & 3) << 1) + (w & 1);    // wave-uniform head

  if (three < 2) {
    u16* dst = three ? k : q;
    const float sc_extra = three ? 1.f : temp[h];
#pragma unroll
    for (int it = 0; it < 4; ++it) {
#pragma unroll
      for (int r = 0; r < 4; ++r) {
        float s = 0.f;
#pragma unroll
        for (int jt = 0; jt < 6; ++jt) s += acc[it][jt][r] * acc[it][jt][r];
        s += __shfl_xor(s, 1); s += __shfl_xor(s, 2);
        s += __shfl_xor(s, 4); s += __shfl_xor(s, 8);
        const float scale = sc_extra / fmaxf(sqrtf(s), 1e-12f);
        const int m = m0 + wm + it * 16 + quad * 4 + r;
        const int b = m >> 10, n = m & 1023;
        u16* rowp = dst + ((size_t)(b * 8 + h) * 1024 + n) * 96;
#pragma unroll
        for (int jt = 0; jt < 6; ++jt)
          rowp[jt * 16 + i15] = f2b(acc[it][jt][r] * scale);
      }
    }
  } else {
#pragma unroll
    for (int it = 0; it < 4; ++it) {
      const int mb4 = m0 + wm + it * 16 + quad * 4;
      const int b = mb4 >> 10, nbase = mb4 & 1023;
#pragma unroll
      for (int jt = 0; jt < 6; ++jt) {
        const int d = jt * 16 + i15;
        uint2 pk;
        pk.x = (u32)f2b(acc[it][jt][0]) | ((u32)f2b(acc[it][jt][1]) << 16);
        pk.y = (u32)f2b(acc[it][jt][2]) | ((u32)f2b(acc[it][jt][3]) << 16);
        *(uint2*)(vT + ((size_t)(b * 8 + h) * 96 + d) * 1024 + nbase) = pk;
      }
    }
  }
}

// ---------------- fused attention, bf16 MFMA, no-max online softmax ---------
// Block = (bh, 128 q-rows); bh = blockIdx&63 so the 8 q-blocks of one bh share
// an XCD (L2-resident K/V). S^T = K*Q^T (C-regs = 4 consecutive keys) -> exp ->
// packed b64 into per-wave Ps -> PV with A=P, B=V^T. swz() granule XOR layouts.
__global__ __launch_bounds__(256, 2) void attn_kernel(
    const u16* __restrict__ q, const u16* __restrict__ kk,
    const u16* __restrict__ vT, u16* __restrict__ ctx) {
  __shared__ u16 smem[20480];         // [0,12288): K+V granules; [12288,20480): Ps
  u16* KVs = smem;
  const int tid = threadIdx.x, w = tid >> 6, lane = tid & 63;
  const int i15 = lane & 15, quad = lane >> 4;
  const int xs = swz(i15);
  const int bh = blockIdx.x & 63, qbase = (blockIdx.x >> 6) * 128;
  const int b = bh >> 3, h = bh & 7;
  u16* Pw = smem + 12288 + w * 2048;  // per-wave P: 256 granules

  bf16x8 qf[2][3];
#pragma unroll
  for (int rt = 0; rt < 2; ++rt) {
    const int qrow = qbase + w * 32 + rt * 16 + i15;
    const u16* qp = q + ((size_t)bh * 1024 + qrow) * 96 + quad * 8;
#pragma unroll
    for (int c = 0; c < 3; ++c) qf[rt][c] = *(const bf16x8*)(qp + c * 32);
  }

  f32x4 o[2][6];
#pragma unroll
  for (int rt = 0; rt < 2; ++rt)
#pragma unroll
    for (int dt = 0; dt < 6; ++dt) o[rt][dt] = (f32x4){0.f, 0.f, 0.f, 0.f};
  float l[2] = {0.f, 0.f};

  const int key_s = tid >> 2, qs = tid & 3;
  const int kgq = qs ^ swz(key_s);
  int vd[3], vc2[3], vgq[3];
  vd[0] = tid >> 2;                      vc2[0] = 0;
  vd[1] = (tid < 128) ? (tid >> 2) + 64 : (tid >> 2) - 32;  vc2[1] = (tid >= 128);
  vd[2] = (tid >> 2) + 32;               vc2[2] = 1;
#pragma unroll
  for (int j = 0; j < 3; ++j) vgq[j] = qs ^ swz(vd[j]);

  uint4 kreg[3], vreg[3];
#pragma unroll
  for (int j = 0; j < 3; ++j) {          // prefetch tile 0
    kreg[j] = *(const uint4*)(kk + ((size_t)bh * 1024 + key_s) * 96 + (j * 4 + kgq) * 8);
    vreg[j] = *(const uint4*)(vT + ((size_t)bh * 96 + vd[j]) * 1024 + vc2[j] * 32 + vgq[j] * 8);
  }

  for (int t = 0; t < 16; ++t) {
    __syncthreads();
#pragma unroll
    for (int j = 0; j < 3; ++j) {
      *(uint4*)(KVs + (size_t)(j * 256 + tid) * 8) = kreg[j];
      *(uint4*)(KVs + (size_t)(768 + j * 256 + tid) * 8) = vreg[j];
    }
    __syncthreads();
    if (t < 15) {
      const int kt0 = (t + 1) * 64;
#pragma unroll
      for (int j = 0; j < 3; ++j) {
        kreg[j] = *(const uint4*)(kk + ((size_t)bh * 1024 + kt0 + key_s) * 96 + (j * 4 + kgq) * 8);
        vreg[j] = *(const uint4*)(vT + ((size_t)bh * 96 + vd[j]) * 1024 + kt0 + vc2[j] * 32 + vgq[j] * 8);
      }
    }
    // ---- S^T phase ----
#pragma unroll
    for (int kt = 0; kt < 4; ++kt) {
      bf16x8 af[3];
#pragma unroll
      for (int c = 0; c < 3; ++c)
        af[c] = *(const bf16x8*)(KVs + ((size_t)((c * 64 + kt * 16 + i15) * 4) + (quad ^ xs)) * 8);
#pragma unroll
      for (int rt = 0; rt < 2; ++rt) {
        f32x4 s = (f32x4){0.f, 0.f, 0.f, 0.f};
#pragma unroll
        for (int c = 0; c < 3; ++c)
          s = __builtin_amdgcn_mfma_f32_16x16x32_bf16(af[c], qf[rt][c], s, 0, 0, 0);
        const float e0 = __expf(s[0]), e1 = __expf(s[1]);
        const float e2 = __expf(s[2]), e3 = __expf(s[3]);
        l[rt] += (e0 + e1) + (e2 + e3);
        uint2 pk;
        pk.x = (u32)f2b(e0) | ((u32)f2b(e1) << 16);
        pk.y = (u32)f2b(e2) | ((u32)f2b(e3) << 16);
        const int pg = (kt & 1) * 2 + (quad >> 1);
        *(uint2*)(Pw + (size_t)(((kt >> 1) * 32 + rt * 16 + i15) * 4 + (pg ^ xs)) * 8
                      + (quad & 1) * 4) = pk;
      }
    }
    // ---- PV phase ----
#pragma unroll
    for (int c2 = 0; c2 < 2; ++c2) {
      bf16x8 pa[2];
#pragma unroll
      for (int rt = 0; rt < 2; ++rt)
        pa[rt] = *(const bf16x8*)(Pw + (size_t)((c2 * 32 + rt * 16 + i15) * 4 + (quad ^ xs)) * 8);
#pragma unroll
      for (int dt = 0; dt < 6; ++dt) {
        const bf16x8 vb = *(const bf16x8*)(KVs +
            ((size_t)(768 + (c2 * 96 + dt * 16 + i15) * 4) + (quad ^ xs)) * 8);
#pragma unroll
        for (int rt = 0; rt < 2; ++rt)
          o[rt][dt] = __builtin_amdgcn_mfma_f32_16x16x32_bf16(pa[rt], vb, o[rt][dt], 0, 0, 0);
      }
    }
  }

  l[0] += __shfl_xor(l[0], 16); l[0] += __shfl_xor(l[0], 32);
  l[1] += __shfl_xor(l[1], 16); l[1] += __shfl_xor(l[1], 32);
  __syncthreads();
  u16* scr = smem + w * 5120;            // 32 rows x stride 104
#pragma unroll
  for (int rt = 0; rt < 2; ++rt) {
#pragma unroll
    for (int r = 0; r < 4; ++r) {
      const float linv = 1.f / __shfl(l[rt], quad * 4 + r);
      const int row32 = rt * 16 + quad * 4 + r;
#pragma unroll
      for (int dt = 0; dt < 6; ++dt)
        scr[row32 * 104 + dt * 16 + i15] = f2b(o[rt][dt][r] * linv);
    }
  }
#pragma unroll
  for (int jj = 0; jj < 6; ++jj) {
    const int id = jj * 64 + lane;
    const int row32 = id / 12, g = id - row32 * 12;
    const int grow = b * 1024 + qbase + w * 32 + row32;
    *(uint4*)(ctx + (size_t)grow * 768 + h * 96 + g * 8) =
        *(const uint4*)(scr + row32 * 104 + g * 8);
  }
}

// ---------------- proj GEMM: 128x64 tiles, ctx @ wT + bias -> out fp32 ------
__global__ __launch_bounds__(256, 4) void proj_gemm_kernel(
    const u16* __restrict__ ctx, const u16* __restrict__ wT,
    const float* __restrict__ bias, float* __restrict__ out) {
  f32x4 acc[4][2];
  const int bid = blockIdx.x;                 // 768 blocks = 3/CU exact
  const int xcd = bid & 7, slot = bid >> 3;   // 96 slots per XCD
  const int mb = xcd * 8 + slot / 12, nb = slot % 12;
  const int m0 = mb * 128, n0 = nb * 64;
  gemm_core<64>(ctx, wT, m0, n0, acc);

  const int tid = threadIdx.x, w = tid >> 6, lane = tid & 63;
  const int i15 = lane & 15, quad = lane >> 4;
  const int wm = (w >> 1) * 64, wn = (w & 1) * 32;
#pragma unroll
  for (int jt = 0; jt < 2; ++jt) {
    const int c = n0 + wn + jt * 16 + i15;
    const float bb = bias[c];
#pragma unroll
    for (int it = 0; it < 4; ++it) {
#pragma unroll
      for (int r = 0; r < 4; ++r) {
        const int m = m0 + wm + it * 16 + quad * 4 + r;
        out[(size_t)m * 768 + c] = acc[it][jt][r] + bb;
      }
    }
  }
}

// ---------------- host launcher --------------------------------------------
extern "C" void kernel_launch(void* const* d_in, const int* in_sizes, int n_in,
                              void* d_out, int out_size, void* d_ws, size_t ws_size,
                              hipStream_t stream) {
  const float* x      = (const float*)d_in[0];   // [8,1024,768]
  const float* w_qkv  = (const float*)d_in[1];   // [768,2304]
  const float* temp   = (const float*)d_in[2];   // [8]
  const float* w_proj = (const float*)d_in[3];   // [768,768]
  const float* b_proj = (const float*)d_in[4];   // [768]

  u16* ws      = (u16*)d_ws;
  u16* xb      = ws;                     // 8192*768
  u16* wqkvT   = xb + 6291456;           // 2304*768
  u16* qb      = wqkvT + 1769472;        // 64*1024*96
  u16* kb      = qb + 6291456;
  u16* vTb     = kb + 6291456;           // 64*96*1024 (transposed)
  u16* ctxb    = vTb + 6291456;          // 8192*768
  u16* wprojT  = ctxb + 6291456;         // 768*768

  prep_kernel<<<8448, 256, 0, stream>>>(x, w_qkv, w_proj, xb, wqkvT, wprojT);
  qkv_gemm_kernel<<<768, 256, 0, stream>>>(xb, wqkvT, temp, qb, kb, vTb);
  attn_kernel<<<512, 256, 0, stream>>>(qb, kb, vTb, ctxb);
  proj_gemm_kernel<<<768, 256, 0, stream>>>(ctxb, wprojT, b_proj, (float*)d_out);
}